// Round 4
// baseline (352.858 us; speedup 1.0000x reference)
//
#include <hip/hip_runtime.h>
#include <hip/hip_bf16.h>

#define N_GRAPHS 64

// ---------------------------------------------------------------------------
__global__ void k_deg(const int* __restrict__ dst, int E, int* __restrict__ deg) {
    int i = blockIdx.x * blockDim.x + threadIdx.x;
    if (i < E) atomicAdd(&deg[dst[i]], 1);
}

// dis/xp + per-block deg sums (fused)
__global__ void k_dis_bsum(const int* __restrict__ deg, const float* __restrict__ x,
                           float* __restrict__ dis, float* __restrict__ xp,
                           int* __restrict__ bsum, int N) {
    int i = blockIdx.x * 256 + threadIdx.x;
    int dv = (i < N) ? deg[i] : 0;
    if (i < N) {
        float d = rsqrtf((float)(dv + 1));
        dis[i] = d;
        xp[i]  = d * x[i];
    }
    int v = dv;
#pragma unroll
    for (int o = 1; o < 64; o <<= 1) v += __shfl_xor(v, o);
    __shared__ int ws4[4];
    if ((threadIdx.x & 63) == 0) ws4[threadIdx.x >> 6] = v;
    __syncthreads();
    if (threadIdx.x == 0) bsum[blockIdx.x] = ws4[0] + ws4[1] + ws4[2] + ws4[3];
}

__device__ inline int block_scan_inc(int v, int* wsum) {
    int lane = threadIdx.x & 63, w = threadIdx.x >> 6;
    int iv = v;
#pragma unroll
    for (int o = 1; o < 64; o <<= 1) {
        int t = __shfl_up(iv, o);
        if (lane >= o) iv += t;
    }
    if (lane == 63) wsum[w] = iv;
    __syncthreads();
    int add = 0;
    for (int k = 0; k < w; ++k) add += wsum[k];
    return iv + add;
}

__global__ void k_scan_sums(const int* __restrict__ bsum, int nb, int* __restrict__ boff) {
    __shared__ int wsum[4];
    int tid = threadIdx.x;
    int v = (tid < nb) ? bsum[tid] : 0;
    int inc = block_scan_inc(v, wsum);
    if (tid < nb) boff[tid] = inc - v;   // exclusive
}

__global__ void k_scan_apply(const int* __restrict__ deg, const int* __restrict__ boff,
                             int* __restrict__ row_ptr, int N) {
    __shared__ int wsum[4];
    int b = blockIdx.x, i = b * 256 + threadIdx.x;
    int v = (i < N) ? deg[i] : 0;
    int inc = block_scan_inc(v, wsum) + boff[b];
    if (i < N) {
        row_ptr[i] = inc - v;
        if (i == N - 1) row_ptr[N] = inc;
    }
}

__global__ void k_scatter(const int* __restrict__ src, const int* __restrict__ dst, int E,
                          const int* __restrict__ row_ptr, int* __restrict__ fill,
                          int* __restrict__ csr_src) {
    int e = blockIdx.x * blockDim.x + threadIdx.x;
    if (e < E) {
        int d = dst[e];
        int pos = row_ptr[d] + atomicAdd(&fill[d], 1);
        csr_src[pos] = src[e];
    }
}

// t[d] = dis[d] * ( sum xp[s] + xp[d] )
__global__ void k_agg_scalar(const float* __restrict__ xp, const float* __restrict__ dis,
                             const int* __restrict__ row_ptr, const int* __restrict__ csr,
                             float* __restrict__ t, int N) {
    int d = blockIdx.x * blockDim.x + threadIdx.x;
    if (d >= N) return;
    float acc = xp[d];
    int e0 = row_ptr[d], e1 = row_ptr[d + 1];
    int e = e0;
    for (; e + 8 <= e1; e += 8) {
        int s0 = csr[e],     s1 = csr[e + 1], s2 = csr[e + 2], s3 = csr[e + 3];
        int s4 = csr[e + 4], s5 = csr[e + 5], s6 = csr[e + 6], s7 = csr[e + 7];
        acc += ((xp[s0] + xp[s1]) + (xp[s2] + xp[s3]))
             + ((xp[s4] + xp[s5]) + (xp[s6] + xp[s7]));
    }
    for (; e < e1; ++e) acc += xp[csr[e]];
    t[d] = dis[d] * acc;
}

// h1'[i][j] = dis[i] * relu(t[i]*W1[j] + b1[j])
__global__ void k_h1(const float* __restrict__ t, const float* __restrict__ dis,
                     const float* __restrict__ W1, const float* __restrict__ b1,
                     float* __restrict__ h1, int N) {
    __shared__ float w[128], bb[128];
    const int tid = threadIdx.x;
    if (tid < 128) { w[tid] = W1[tid]; bb[tid] = b1[tid]; }
    __syncthreads();
    int idx = blockIdx.x * 256 + tid;
    if (idx < N * 128) {
        int i = idx >> 7, j = idx & 127;
        float v = fmaf(t[i], w[j], bb[j]);
        h1[idx] = fmaxf(v, 0.f) * dis[i];
    }
}

// out[d][:] = dis[d] * ( sum_{s in N(d)} hp[s][:] + hp[d][:] ),  F = 128
// float4/lane, 32 lanes/node, 8 nodes/block; 8-edge unroll for MLP.
__global__ void k_agg128(const float4* __restrict__ hp4, const float* __restrict__ dis,
                         const int* __restrict__ row_ptr, const int* __restrict__ csr,
                         float4* __restrict__ out4, int N) {
    int node = blockIdx.x * 8 + (threadIdx.x >> 5);
    int lane = threadIdx.x & 31;
    if (node >= N) return;
    float4 self = hp4[(size_t)node * 32 + lane];
    float a0 = self.x, a1 = self.y, a2 = self.z, a3 = self.w;
    int e0 = row_ptr[node], e1 = row_ptr[node + 1];
    int e = e0;
    for (; e + 8 <= e1; e += 8) {
        int s0 = csr[e],     s1 = csr[e + 1], s2 = csr[e + 2], s3 = csr[e + 3];
        int s4 = csr[e + 4], s5 = csr[e + 5], s6 = csr[e + 6], s7 = csr[e + 7];
        float4 v0 = hp4[(size_t)s0 * 32 + lane];
        float4 v1 = hp4[(size_t)s1 * 32 + lane];
        float4 v2 = hp4[(size_t)s2 * 32 + lane];
        float4 v3 = hp4[(size_t)s3 * 32 + lane];
        float4 v4 = hp4[(size_t)s4 * 32 + lane];
        float4 v5 = hp4[(size_t)s5 * 32 + lane];
        float4 v6 = hp4[(size_t)s6 * 32 + lane];
        float4 v7 = hp4[(size_t)s7 * 32 + lane];
        a0 += ((v0.x + v1.x) + (v2.x + v3.x)) + ((v4.x + v5.x) + (v6.x + v7.x));
        a1 += ((v0.y + v1.y) + (v2.y + v3.y)) + ((v4.y + v5.y) + (v6.y + v7.y));
        a2 += ((v0.z + v1.z) + (v2.z + v3.z)) + ((v4.z + v5.z) + (v6.z + v7.z));
        a3 += ((v0.w + v1.w) + (v2.w + v3.w)) + ((v4.w + v5.w) + (v6.w + v7.w));
    }
    for (; e < e1; ++e) {
        int s = csr[e];
        float4 v = hp4[(size_t)s * 32 + lane];
        a0 += v.x; a1 += v.y; a2 += v.z; a3 += v.w;
    }
    float d = dis[node];
    out4[(size_t)node * 32 + lane] = make_float4(a0 * d, a1 * d, a2 * d, a3 * d);
}

// GEMM: tile 128 nodes x 128 cols, 128 threads (2 waves), per-thread 8n x 16c.
// K=128 chunked by 32; At[k][n] transposed (b128 reads of 8 nodes), Wl[k][j].
// Per k: 2 A-reads (2-way alias, free) + 4 W-reads (conflict-free broadcast)
// per 128 FMAs -> LDS pipe ~ balanced with VALU.
// FUSE_MAX: skip the store; relu -> per-graph max -> shfl-reduce -> atomicMax.
template<int FOUT, bool SCALE, bool FUSE_MAX>
__global__ __launch_bounds__(128, 2) void k_gemm(
        const float* __restrict__ A, const float* __restrict__ W,
        const float* __restrict__ b, const float* __restrict__ dis,
        float* __restrict__ out, const int* __restrict__ batch,
        unsigned int* __restrict__ gmax, int N) {
    __shared__ float At[32][132];
    __shared__ float Wl[32][132];
    const int tid = threadIdx.x;
    const int n0 = blockIdx.x * 128;
    const int jh = blockIdx.y;
    const int ng = tid >> 3;   // 0..15 -> nodes ng*8..+7
    const int cg = tid & 7;    // 0..7  -> cols cg*4 + {0,32,64,96} +0..3

    float acc[8][16] = {};

    for (int kc = 0; kc < 128; kc += 32) {
        // stage A^T chunk: At[kk][nn] = A[n0+nn][kc+kk]
        for (int idx = tid; idx < 1024; idx += 128) {
            int nn = idx >> 3, q = idx & 7;
            int node = n0 + nn;
            float4 a = (node < N)
                ? reinterpret_cast<const float4*>(A + (size_t)node * 128 + kc)[q]
                : make_float4(0.f, 0.f, 0.f, 0.f);
            At[q * 4 + 0][nn] = a.x;
            At[q * 4 + 1][nn] = a.y;
            At[q * 4 + 2][nn] = a.z;
            At[q * 4 + 3][nn] = a.w;
        }
        // stage W chunk: Wl[kk][j] = W[(kc+kk)*FOUT + jh*128 + j]
        for (int idx = tid; idx < 1024; idx += 128) {
            int kk = idx >> 5, jc = idx & 31;
            float4 w = reinterpret_cast<const float4*>(
                W + (size_t)(kc + kk) * FOUT + jh * 128)[jc];
            *reinterpret_cast<float4*>(&Wl[kk][jc * 4]) = w;
        }
        __syncthreads();

#pragma unroll 2
        for (int k = 0; k < 32; ++k) {
            float4 a0 = *reinterpret_cast<const float4*>(&At[k][ng * 8]);
            float4 a1 = *reinterpret_cast<const float4*>(&At[k][ng * 8 + 4]);
            float4 w0 = *reinterpret_cast<const float4*>(&Wl[k][cg * 4]);
            float4 w1 = *reinterpret_cast<const float4*>(&Wl[k][cg * 4 + 32]);
            float4 w2 = *reinterpret_cast<const float4*>(&Wl[k][cg * 4 + 64]);
            float4 w3 = *reinterpret_cast<const float4*>(&Wl[k][cg * 4 + 96]);
            const float av[8]  = {a0.x,a0.y,a0.z,a0.w,a1.x,a1.y,a1.z,a1.w};
            const float wv[16] = {w0.x,w0.y,w0.z,w0.w,w1.x,w1.y,w1.z,w1.w,
                                  w2.x,w2.y,w2.z,w2.w,w3.x,w3.y,w3.z,w3.w};
#pragma unroll
            for (int i = 0; i < 8; ++i)
#pragma unroll
                for (int j = 0; j < 16; ++j)
                    acc[i][j] = fmaf(av[i], wv[j], acc[i][j]);
        }
        __syncthreads();
    }

    float bb[16];
#pragma unroll
    for (int s = 0; s < 4; ++s)
#pragma unroll
        for (int r = 0; r < 4; ++r)
            bb[s * 4 + r] = b[jh * 128 + cg * 4 + 32 * s + r];

    if (!FUSE_MAX) {
#pragma unroll
        for (int i = 0; i < 8; ++i) {
            int node = n0 + ng * 8 + i;
            if (node < N) {
                float dsc = SCALE ? dis[node] : 1.f;
                float o[16];
#pragma unroll
                for (int j = 0; j < 16; ++j) {
                    float v = fmaxf(acc[i][j] + bb[j], 0.f);
                    o[j] = SCALE ? v * dsc : v;
                }
                float* op = out + (size_t)node * FOUT + jh * 128;
#pragma unroll
                for (int s = 0; s < 4; ++s)
                    *reinterpret_cast<float4*>(op + cg * 4 + 32 * s) =
                        make_float4(o[s*4], o[s*4+1], o[s*4+2], o[s*4+3]);
            }
        }
    } else {
        // relu in registers
#pragma unroll
        for (int i = 0; i < 8; ++i)
#pragma unroll
            for (int j = 0; j < 16; ++j)
                acc[i][j] = fmaxf(acc[i][j] + bb[j], 0.f);
        int gfirst = batch[n0];
        int glast  = batch[min(n0 + 127, N - 1)];
        int nb[8];
#pragma unroll
        for (int i = 0; i < 8; ++i) {
            int node = n0 + ng * 8 + i;
            nb[i] = (node < N) ? batch[node] : -1;
        }
        for (int gb = gfirst; gb <= glast; ++gb) {
            float m[16];
#pragma unroll
            for (int j = 0; j < 16; ++j) m[j] = 0.f;
#pragma unroll
            for (int i = 0; i < 8; ++i)
                if (nb[i] == gb)
#pragma unroll
                    for (int j = 0; j < 16; ++j) m[j] = fmaxf(m[j], acc[i][j]);
            // reduce along ng within the wave (lane bits 3..5)
#pragma unroll
            for (int j = 0; j < 16; ++j) {
                m[j] = fmaxf(m[j], __shfl_xor(m[j], 8));
                m[j] = fmaxf(m[j], __shfl_xor(m[j], 16));
                m[j] = fmaxf(m[j], __shfl_xor(m[j], 32));
            }
            if ((tid & 56) == 0) {   // one lane per (wave, cg)
#pragma unroll
                for (int s = 0; s < 4; ++s)
#pragma unroll
                    for (int r = 0; r < 4; ++r)
                        atomicMax(&gmax[gb * 256 + jh * 128 + cg * 4 + 32 * s + r],
                                  __float_as_uint(m[s * 4 + r]));
            }
        }
    }
}

// final MLP: out = relu( relu(g@Wf1+bf1) @ Wf2 + bf2 )
__global__ void k_mlp(const float* __restrict__ g, const float* __restrict__ Wf1,
                      const float* __restrict__ bf1, const float* __restrict__ Wf2,
                      const float* __restrict__ bf2, float* __restrict__ out) {
    __shared__ float gr[256];
    __shared__ float g1s[128];
    const int gid = blockIdx.x;
    const int tid = threadIdx.x;
    gr[tid] = g[gid * 256 + tid];
    gr[tid + 128] = g[gid * 256 + 128 + tid];
    __syncthreads();
    float acc = bf1[tid];
    for (int k = 0; k < 256; ++k)
        acc = fmaf(gr[k], Wf1[k * 128 + tid], acc);
    g1s[tid] = fmaxf(acc, 0.f);
    __syncthreads();
    if (tid < 10) {
        float a = bf2[tid];
        for (int k = 0; k < 128; ++k)
            a = fmaf(g1s[k], Wf2[k * 10 + tid], a);
        out[gid * 10 + tid] = fmaxf(a, 0.f);
    }
}

// ---------------------------------------------------------------------------
extern "C" void kernel_launch(void* const* d_in, const int* in_sizes, int n_in,
                              void* d_out, int out_size, void* d_ws, size_t ws_size,
                              hipStream_t stream) {
    const float* x   = (const float*)d_in[0];
    const int*   ei  = (const int*)d_in[1];
    const int*   bat = (const int*)d_in[2];
    const float* W1  = (const float*)d_in[3];
    const float* b1  = (const float*)d_in[4];
    const float* W2  = (const float*)d_in[5];
    const float* b2  = (const float*)d_in[6];
    const float* W3  = (const float*)d_in[7];
    const float* b3  = (const float*)d_in[8];
    const float* Wf1 = (const float*)d_in[9];
    const float* bf1 = (const float*)d_in[10];
    const float* Wf2 = (const float*)d_in[11];
    const float* bf2 = (const float*)d_in[12];
    float* out = (float*)d_out;

    const int N = in_sizes[0];          // 50000
    const int E = in_sizes[1] / 2;      // 800000
    const int* src = ei;
    const int* dst = ei + E;

    char* base = (char*)d_ws;
    size_t off = 0;
    auto carve = [&](size_t bytes) -> char* {
        char* p = base + off;
        off = (off + bytes + 255) & ~(size_t)255;
        return p;
    };
    const int nb = (N + 255) / 256;
    int*   deg     = (int*)  carve((size_t)N * 4);
    int*   fill    = (int*)  carve((size_t)N * 4);
    int*   row_ptr = (int*)  carve((size_t)(N + 1) * 4);
    int*   csr     = (int*)  carve((size_t)E * 4);
    float* dis     = (float*)carve((size_t)N * 4);
    float* xp      = (float*)carve((size_t)N * 4);
    float* t       = (float*)carve((size_t)N * 4);
    float* B1      = (float*)carve((size_t)N * 128 * 4);
    float* B2      = (float*)carve((size_t)N * 128 * 4);
    unsigned int* g = (unsigned int*)carve((size_t)N_GRAPHS * 256 * 4);
    int*   bsum    = (int*)  carve((size_t)nb * 4);
    int*   boff    = (int*)  carve((size_t)nb * 4);
    (void)ws_size; (void)n_in; (void)out_size;

    hipMemsetAsync(deg, 0, (size_t)N * 4, stream);
    hipMemsetAsync(fill, 0, (size_t)N * 4, stream);
    hipMemsetAsync(g, 0, (size_t)N_GRAPHS * 256 * 4, stream);

    int eb = (E + 255) / 256;

    k_deg<<<eb, 256, 0, stream>>>(dst, E, deg);
    k_dis_bsum<<<nb, 256, 0, stream>>>(deg, x, dis, xp, bsum, N);
    k_scan_sums<<<1, 256, 0, stream>>>(bsum, nb, boff);
    k_scan_apply<<<nb, 256, 0, stream>>>(deg, boff, row_ptr, N);
    k_scatter<<<eb, 256, 0, stream>>>(src, dst, E, row_ptr, fill, csr);

    k_agg_scalar<<<nb, 256, 0, stream>>>(xp, dis, row_ptr, csr, t, N);
    k_h1<<<(N * 128 + 255) / 256, 256, 0, stream>>>(t, dis, W1, b1, B1, N);

    const int gx = (N + 127) / 128;
    k_agg128<<<(N + 7) / 8, 256, 0, stream>>>((const float4*)B1, dis, row_ptr, csr,
                                              (float4*)B2, N);
    k_gemm<128, true, false><<<dim3(gx, 1), 128, 0, stream>>>(
        B2, W2, b2, dis, B1, nullptr, nullptr, N);

    k_agg128<<<(N + 7) / 8, 256, 0, stream>>>((const float4*)B1, dis, row_ptr, csr,
                                              (float4*)B2, N);
    k_gemm<256, false, true><<<dim3(gx, 2), 128, 0, stream>>>(
        B2, W3, b3, nullptr, nullptr, bat, g, N);

    k_mlp<<<N_GRAPHS, 128, 0, stream>>>((const float*)g, Wf1, bf1, Wf2, bf2, out);
}